// Round 1
// baseline (695.405 us; speedup 1.0000x reference)
//
#include <hip/hip_runtime.h>
#include <math.h>

// Problem constants (fixed shapes: B=512, N=256)
#define NB 512
#define NN 256

constexpr float C_ERF  = 0.88622692545275801f;   // sqrt(pi)/2
constexpr float SQRTL  = 0.22360679774997896f;   // sqrt(0.05)

// 16-point Gauss-Legendre nodes/weights (np.polynomial.legendre.leggauss(16))
__device__ __constant__ float GLN[16] = {
  -0.98940093499164993f, -0.94457502307323258f, -0.86563120238783174f,
  -0.75540440835500303f, -0.61787624440264375f, -0.45801677765722739f,
  -0.28160355077925891f, -0.09501250983763744f,  0.09501250983763744f,
   0.28160355077925891f,  0.45801677765722739f,  0.61787624440264375f,
   0.75540440835500303f,  0.86563120238783174f,  0.94457502307323258f,
   0.98940093499164993f };
__device__ __constant__ float GLW[16] = {
   0.02715245941175409f, 0.06225352393864789f, 0.09515851168249278f,
   0.12462897125553387f, 0.14959598881657673f, 0.16915651939500254f,
   0.18260341504492358f, 0.18945061045506850f, 0.18945061045506850f,
   0.18260341504492358f, 0.16915651939500254f, 0.14959598881657673f,
   0.12462897125553387f, 0.09515851168249278f, 0.06225352393864789f,
   0.02715245941175409f };

// g(x) = exp(x^2) * sqrt(pi)/2 * (1+erf(x)) ; 1+erf(x)=erfc(-x) (relative accuracy!)
__device__ __forceinline__ float gfun(float x) {
  return __expf(x * x) * (C_ERF * erfcf(-x));
}

// ---------------- u2 = u @ W^T + b ----------------
__global__ __launch_bounds__(256) void k_u2(const float* __restrict__ u,
                                            const float* __restrict__ W,
                                            const float* __restrict__ bias,
                                            float* __restrict__ u2) {
  int b = blockIdx.x, t = threadIdx.x;
  __shared__ __align__(16) float su[NN];
  su[t] = u[b * NN + t];
  __syncthreads();
  const float4* su4 = (const float4*)su;
  const float4* W4  = (const float4*)(W + t * NN);
  float acc = bias[t];
  #pragma unroll 8
  for (int i = 0; i < NN / 4; ++i) {
    float4 wv = W4[i];
    float4 uv = su4[i];
    acc = fmaf(wv.x, uv.x, acc); acc = fmaf(wv.y, uv.y, acc);
    acc = fmaf(wv.z, uv.z, acc); acc = fmaf(wv.w, uv.w, acc);
  }
  u2[b * NN + t] = acc;
}

// ---------------- BatchNorm stats over batch ----------------
__global__ __launch_bounds__(256) void k_bn(const float* __restrict__ u2,
                                            const float* __restrict__ gamma,
                                            float* __restrict__ muv,
                                            float* __restrict__ invv) {
  int o = blockIdx.x, t = threadIdx.x;
  float v1 = u2[t * NN + o];
  float v2 = u2[(t + 256) * NN + o];
  __shared__ float rs[256], rq[256];
  rs[t] = v1 + v2;
  rq[t] = v1 * v1 + v2 * v2;
  __syncthreads();
  for (int off = 128; off > 0; off >>= 1) {
    if (t < off) { rs[t] += rs[t + off]; rq[t] += rq[t + off]; }
    __syncthreads();
  }
  if (t == 0) {
    float m   = rs[0] * (1.0f / NB);
    float var = rq[0] * (1.0f / NB) - m * m;
    muv[o]  = m;
    invv[o] = gamma[o] * rsqrtf(var + 1e-5f);
  }
}

// ---------------- GEMM1: T[b] = (W*diag(s_b)) @ R[b]  (128x128 tile, 8x8/thread) ----------------
__global__ __launch_bounds__(256) void k_gemm1(const float* __restrict__ W,
                                               const float* __restrict__ s,
                                               const float* __restrict__ rho,
                                               float* __restrict__ T, int c0) {
  int o0 = blockIdx.x * 128, j0 = blockIdx.y * 128;
  int bl = blockIdx.z, bg = c0 + bl;
  const float* Rb = rho + (size_t)bg * (NN * NN);
  const float* sb = s + bg * NN;
  __shared__ __align__(16) float As[16][132];
  __shared__ __align__(16) float Bs[16][132];
  int t = threadIdx.x;
  int tx = t & 15, ty = t >> 4;
  int qa = t & 3, ra = t >> 2;          // A staging: k-quad, row
  int rb = t >> 4, cb8 = (t & 15) * 8;  // B staging: k-row, col
  float acc[8][8] = {};
  for (int kk = 0; kk < NN; kk += 16) {
    float4 sv = *(const float4*)(sb + kk + qa * 4);
    float4 a0 = *(const float4*)(W + (o0 + ra) * NN + kk + qa * 4);
    float4 a1 = *(const float4*)(W + (o0 + ra + 64) * NN + kk + qa * 4);
    float4 b0 = *(const float4*)(Rb + (kk + rb) * NN + j0 + cb8);
    float4 b1 = *(const float4*)(Rb + (kk + rb) * NN + j0 + cb8 + 4);
    __syncthreads();
    As[qa * 4 + 0][ra] = a0.x * sv.x; As[qa * 4 + 1][ra] = a0.y * sv.y;
    As[qa * 4 + 2][ra] = a0.z * sv.z; As[qa * 4 + 3][ra] = a0.w * sv.w;
    As[qa * 4 + 0][ra + 64] = a1.x * sv.x; As[qa * 4 + 1][ra + 64] = a1.y * sv.y;
    As[qa * 4 + 2][ra + 64] = a1.z * sv.z; As[qa * 4 + 3][ra + 64] = a1.w * sv.w;
    *(float4*)&Bs[rb][cb8]     = b0;
    *(float4*)&Bs[rb][cb8 + 4] = b1;
    __syncthreads();
    #pragma unroll
    for (int k = 0; k < 16; ++k) {
      float4 av0 = *(const float4*)&As[k][ty * 4];
      float4 av1 = *(const float4*)&As[k][ty * 4 + 64];
      float4 bv0 = *(const float4*)&Bs[k][tx * 4];
      float4 bv1 = *(const float4*)&Bs[k][tx * 4 + 64];
      float am[8] = {av0.x, av0.y, av0.z, av0.w, av1.x, av1.y, av1.z, av1.w};
      float bm[8] = {bv0.x, bv0.y, bv0.z, bv0.w, bv1.x, bv1.y, bv1.z, bv1.w};
      #pragma unroll
      for (int m = 0; m < 8; ++m)
        #pragma unroll
        for (int n = 0; n < 8; ++n)
          acc[m][n] = fmaf(am[m], bm[n], acc[m][n]);
    }
  }
  float* Tb = T + (size_t)bl * (NN * NN);
  #pragma unroll
  for (int m = 0; m < 8; ++m) {
    int row = o0 + ty * 4 + (m & 3) + (m >> 2) * 64;
    *(float4*)(Tb + row * NN + j0 + tx * 4)      = make_float4(acc[m][0], acc[m][1], acc[m][2], acc[m][3]);
    *(float4*)(Tb + row * NN + j0 + tx * 4 + 64) = make_float4(acc[m][4], acc[m][5], acc[m][6], acc[m][7]);
  }
}

// ---------------- diag: s2[b,o] = sqrt(max(sum_j T[b,o,j]*W[o,j]*s[b,j],0)) ----------------
__global__ __launch_bounds__(256) void k_diag(const float* __restrict__ T,
                                              const float* __restrict__ W,
                                              const float* __restrict__ s,
                                              float* __restrict__ s2v, int c0) {
  int wid = threadIdx.x >> 6, lane = threadIdx.x & 63;
  int idx = blockIdx.x * 4 + wid;       // local element index within chunk
  int bl = idx >> 8, o = idx & 255;
  int bg = c0 + bl;
  const float* Trow = T + (size_t)bl * (NN * NN) + o * NN;
  const float* Wrow = W + o * NN;
  const float* sb = s + bg * NN;
  float4 tv = *(const float4*)(Trow + lane * 4);
  float4 wv = *(const float4*)(Wrow + lane * 4);
  float4 sv = *(const float4*)(sb + lane * 4);
  float p = tv.x * wv.x * sv.x + tv.y * wv.y * sv.y +
            tv.z * wv.z * sv.z + tv.w * wv.w * sv.w;
  for (int off = 32; off; off >>= 1) p += __shfl_down(p, off, 64);
  if (lane == 0) s2v[bg * NN + o] = sqrtf(fmaxf(p, 0.0f));
}

// ---------------- moment activation: u_a, s_a, chi ----------------
__global__ __launch_bounds__(256) void k_act(const float* __restrict__ u2,
                                             const float* __restrict__ muv,
                                             const float* __restrict__ invv,
                                             const float* __restrict__ beta,
                                             const float* __restrict__ s2v,
                                             float* __restrict__ out_ua,
                                             float* __restrict__ out_sa,
                                             float* __restrict__ chiv, int c0) {
  int o = threadIdx.x;
  int bg = c0 + blockIdx.x;
  int id = bg * NN + o;
  float iv  = invv[o];
  float ubn = fmaf(u2[id] - muv[o], iv, beta[o]);
  float sbn = s2v[id] * fabsf(iv);

  float ss = fmaxf(sbn, 1e-6f);
  float isl = 1.0f / (ss * SQRTL);
  float ub = fminf(fmaxf((1.0f - ubn) * isl, -4.0f), 4.0f);
  float lb = fminf(fmaxf((0.0f - ubn) * isl, -4.0f), 4.0f);
  float mid = 0.5f * (ub + lb), haf = 0.5f * (ub - lb);

  float I1 = 0.0f, V = 0.0f;
  for (int k = 0; k < 16; ++k) {
    float x  = fmaf(haf, GLN[k], mid);
    float Ex = __expf(x * x);
    float ek = C_ERF * erfcf(-x);
    I1 = fmaf(GLW[k], Ex * ek, I1);
    float hm = 0.5f * (x + 4.0f);
    float tb = 0.5f * (x - 4.0f);
    float hs = 0.0f;
    #pragma unroll 4
    for (int j = 0; j < 16; ++j) {
      float tt = fmaf(hm, GLN[j], tb);
      float e  = C_ERF * erfcf(-tt);
      hs = fmaf(GLW[j], __expf(tt * tt) * e * e, hs);
    }
    V = fmaf(GLW[k], Ex * (hm * hs), V);
  }
  I1 *= haf; V *= haf;
  float u_a  = 1.0f / fmaf(40.0f, I1, 5.0f);
  float varT = 3200.0f * V;
  float s_a  = sqrtf(fmaxf(u_a * u_a * u_a * varT, 0.0f));
  float chi  = u_a * u_a * 40.0f * (gfun(ub) - gfun(lb)) /
               (SQRTL * fmaxf(s_a, 1e-6f));
  out_ua[id] = u_a;
  out_sa[id] = s_a;
  chiv[id]   = chi;
}

// ---------------- GEMM2: rho_a[b] = scale(T[b] @ (W*diag(s_b))^T) ----------------
__global__ __launch_bounds__(256) void k_gemm2(const float* __restrict__ T,
                                               const float* __restrict__ W,
                                               const float* __restrict__ s,
                                               const float* __restrict__ s2v,
                                               const float* __restrict__ chiv,
                                               float* __restrict__ out_rho, int c0) {
  int o0 = blockIdx.x * 128, p0 = blockIdx.y * 128;
  int bl = blockIdx.z, bg = c0 + bl;
  const float* Tb = T + (size_t)bl * (NN * NN);
  const float* sb = s + bg * NN;
  __shared__ __align__(16) float As[16][132];
  __shared__ __align__(16) float Bs[16][132];
  int t = threadIdx.x;
  int tx = t & 15, ty = t >> 4;
  int qa = t & 3, ra = t >> 2;
  float acc[8][8] = {};
  for (int kk = 0; kk < NN; kk += 16) {
    // A-tile: T rows (K = j runs along rows of T)
    float4 a0 = *(const float4*)(Tb + (o0 + ra) * NN + kk + qa * 4);
    float4 a1 = *(const float4*)(Tb + (o0 + ra + 64) * NN + kk + qa * 4);
    // B-tile: Ws rows (p)
    float4 sv = *(const float4*)(sb + kk + qa * 4);
    float4 b0 = *(const float4*)(W + (p0 + ra) * NN + kk + qa * 4);
    float4 b1 = *(const float4*)(W + (p0 + ra + 64) * NN + kk + qa * 4);
    __syncthreads();
    As[qa * 4 + 0][ra] = a0.x; As[qa * 4 + 1][ra] = a0.y;
    As[qa * 4 + 2][ra] = a0.z; As[qa * 4 + 3][ra] = a0.w;
    As[qa * 4 + 0][ra + 64] = a1.x; As[qa * 4 + 1][ra + 64] = a1.y;
    As[qa * 4 + 2][ra + 64] = a1.z; As[qa * 4 + 3][ra + 64] = a1.w;
    Bs[qa * 4 + 0][ra] = b0.x * sv.x; Bs[qa * 4 + 1][ra] = b0.y * sv.y;
    Bs[qa * 4 + 2][ra] = b0.z * sv.z; Bs[qa * 4 + 3][ra] = b0.w * sv.w;
    Bs[qa * 4 + 0][ra + 64] = b1.x * sv.x; Bs[qa * 4 + 1][ra + 64] = b1.y * sv.y;
    Bs[qa * 4 + 2][ra + 64] = b1.z * sv.z; Bs[qa * 4 + 3][ra + 64] = b1.w * sv.w;
    __syncthreads();
    #pragma unroll
    for (int k = 0; k < 16; ++k) {
      float4 av0 = *(const float4*)&As[k][ty * 4];
      float4 av1 = *(const float4*)&As[k][ty * 4 + 64];
      float4 bv0 = *(const float4*)&Bs[k][tx * 4];
      float4 bv1 = *(const float4*)&Bs[k][tx * 4 + 64];
      float am[8] = {av0.x, av0.y, av0.z, av0.w, av1.x, av1.y, av1.z, av1.w};
      float bm[8] = {bv0.x, bv0.y, bv0.z, bv0.w, bv1.x, bv1.y, bv1.z, bv1.w};
      #pragma unroll
      for (int m = 0; m < 8; ++m)
        #pragma unroll
        for (int n = 0; n < 8; ++n)
          acc[m][n] = fmaf(am[m], bm[n], acc[m][n]);
    }
  }
  // epilogue: rho_a = cov * chi_o*chi_p / (s2_o*s2_p + 1e-12), diag = 1
  float chio[8], szo[8], chip[8], szp[8];
  #pragma unroll
  for (int m = 0; m < 8; ++m) {
    int o = o0 + ty * 4 + (m & 3) + (m >> 2) * 64;
    chio[m] = chiv[bg * NN + o]; szo[m] = s2v[bg * NN + o];
  }
  #pragma unroll
  for (int n = 0; n < 8; ++n) {
    int p = p0 + tx * 4 + (n & 3) + (n >> 2) * 64;
    chip[n] = chiv[bg * NN + p]; szp[n] = s2v[bg * NN + p];
  }
  float* Ob = out_rho + (size_t)bg * (NN * NN);
  #pragma unroll
  for (int m = 0; m < 8; ++m) {
    int o = o0 + ty * 4 + (m & 3) + (m >> 2) * 64;
    float v[8];
    #pragma unroll
    for (int n = 0; n < 8; ++n) {
      int p = p0 + tx * 4 + (n & 3) + (n >> 2) * 64;
      float val = acc[m][n] * chio[m] * chip[n] / (szo[m] * szp[n] + 1e-12f);
      v[n] = (o == p) ? 1.0f : val;
    }
    *(float4*)(Ob + o * NN + p0 + tx * 4)      = make_float4(v[0], v[1], v[2], v[3]);
    *(float4*)(Ob + o * NN + p0 + tx * 4 + 64) = make_float4(v[4], v[5], v[6], v[7]);
  }
}

extern "C" void kernel_launch(void* const* d_in, const int* in_sizes, int n_in,
                              void* d_out, int out_size, void* d_ws, size_t ws_size,
                              hipStream_t stream) {
  (void)in_sizes; (void)n_in; (void)out_size;
  const float* u     = (const float*)d_in[0];
  const float* s     = (const float*)d_in[1];
  const float* rho   = (const float*)d_in[2];
  const float* W     = (const float*)d_in[3];
  const float* bias  = (const float*)d_in[4];
  const float* gamma = (const float*)d_in[5];
  const float* beta  = (const float*)d_in[6];

  float* out_ua  = (float*)d_out;
  float* out_sa  = out_ua + NB * NN;
  float* out_rho = out_sa + NB * NN;

  // workspace layout
  float* u2   = (float*)d_ws;
  float* s2v  = u2 + NB * NN;
  float* chiv = s2v + NB * NN;
  float* muv  = chiv + NB * NN;
  float* invv = muv + NN;
  float* T    = invv + NN;    // remaining space: per-batch-chunk T buffers
  size_t used = (size_t)((char*)T - (char*)d_ws);
  size_t rem  = ws_size > used ? ws_size - used : 0;
  int chunk = (int)(rem / ((size_t)NN * NN * 4));
  if (chunk > NB) chunk = NB;
  if (chunk < 1) chunk = 1;

  k_u2<<<NB, 256, 0, stream>>>(u, W, bias, u2);
  k_bn<<<NN, 256, 0, stream>>>(u2, gamma, muv, invv);

  for (int c0 = 0; c0 < NB; c0 += chunk) {
    int cb = (NB - c0) < chunk ? (NB - c0) : chunk;
    dim3 gg(2, 2, cb);
    k_gemm1<<<gg, 256, 0, stream>>>(W, s, rho, T, c0);
    k_diag<<<cb * 64, 256, 0, stream>>>(T, W, s, s2v, c0);
    k_act<<<cb, 256, 0, stream>>>(u2, muv, invv, beta, s2v, out_ua, out_sa, chiv, c0);
    k_gemm2<<<gg, 256, 0, stream>>>(T, W, s, s2v, chiv, out_rho, c0);
  }
}

// Round 3
// 446.926 us; speedup vs baseline: 1.5560x; 1.5560x over previous
//
#include <hip/hip_runtime.h>
#include <math.h>

#define NB 512
#define NN 256

typedef __bf16 bf16x8 __attribute__((ext_vector_type(8)));
typedef float f32x16 __attribute__((ext_vector_type(16)));

constexpr float C_ERF   = 0.88622692545275801f;   // sqrt(pi)/2
constexpr float SQRT_PI = 1.77245385090551603f;
constexpr float SQRTL   = 0.22360679774997896f;   // sqrt(0.05)

__device__ __constant__ float GLN[16] = {
  -0.98940093499164993f, -0.94457502307323258f, -0.86563120238783174f,
  -0.75540440835500303f, -0.61787624440264375f, -0.45801677765722739f,
  -0.28160355077925891f, -0.09501250983763744f,  0.09501250983763744f,
   0.28160355077925891f,  0.45801677765722739f,  0.61787624440264375f,
   0.75540440835500303f,  0.86563120238783174f,  0.94457502307323258f,
   0.98940093499164993f };
__device__ __constant__ float GLW[16] = {
   0.02715245941175409f, 0.06225352393864789f, 0.09515851168249278f,
   0.12462897125553387f, 0.14959598881657673f, 0.16915651939500254f,
   0.18260341504492358f, 0.18945061045506850f, 0.18945061045506850f,
   0.18260341504492358f, 0.16915651939500254f, 0.14959598881657673f,
   0.12462897125553387f, 0.09515851168249278f, 0.06225352393864789f,
   0.02715245941175409f };

// ---------- fast scaled complementary error function ----------
// P(z) = sqrt(pi)/2 * erfcx(z), z >= 0  (NR rational, rel err ~1e-6)
__device__ __forceinline__ float fast_P(float z) {
  float r = __builtin_amdgcn_rcpf(fmaf(0.5f, z, 1.0f));
  float p = fmaf(r, 0.17087277f, -0.82215223f);
  p = fmaf(r, p, 1.48851587f);
  p = fmaf(r, p, -1.13520398f);
  p = fmaf(r, p, 0.27886807f);
  p = fmaf(r, p, -0.18628806f);
  p = fmaf(r, p, 0.09678418f);
  p = fmaf(r, p, 0.37409196f);
  p = fmaf(r, p, 1.00002368f);
  p = fmaf(r, p, -1.26551223f);
  return C_ERF * r * __expf(p);
}
// EE(x) = exp(x^2) * sqrt(pi)/2 * erfc(-x), given E = exp(x^2)
__device__ __forceinline__ float fast_EE(float x, float E) {
  float P = fast_P(fabsf(x));
  return x <= 0.0f ? P : fmaf(SQRT_PI, E, -P);
}

// ---------- bf16 split helpers (hi = round-nearest, lo = round-nearest residual) ----------
__device__ __forceinline__ uint bfrn(float x) {
  uint u = __float_as_uint(x);
  return (u + 0x7fffu + ((u >> 16) & 1u)) >> 16;
}
__device__ __forceinline__ uint packhi(float a, float b) {
  return bfrn(a) | (bfrn(b) << 16);     // rounded hi halves (|residual| <= 2^-8 |a|)
}
__device__ __forceinline__ uint packlo(float a, float b, uint h) {
  float af = __uint_as_float(h << 16);
  float bf = __uint_as_float(h & 0xffff0000u);
  return bfrn(a - af) | (bfrn(b - bf) << 16);
}
// stage 8 consecutive-k floats of one row into MFMA-fragment-ordered LDS planes
__device__ __forceinline__ void stage8(ushort* hiP, ushort* loP, int row, int halfk,
                                       float4 f0, float4 f1) {
  uint h0 = packhi(f0.x, f0.y), h1 = packhi(f0.z, f0.w);
  uint h2 = packhi(f1.x, f1.y), h3 = packhi(f1.z, f1.w);
  uint l0 = packlo(f0.x, f0.y, h0), l1 = packlo(f0.z, f0.w, h1);
  uint l2 = packlo(f1.x, f1.y, h2), l3 = packlo(f1.z, f1.w, h3);
  int lane = halfk * 32 + (row & 31);
  int base = ((row >> 5) * 64 + lane) * 8;   // ushort index, 16B-aligned units
  *(uint4*)&hiP[base] = make_uint4(h0, h1, h2, h3);
  *(uint4*)&loP[base] = make_uint4(l0, l1, l2, l3);
}

// ---------------- u2 = u @ W^T + b ----------------
__global__ __launch_bounds__(256) void k_u2(const float* __restrict__ u,
                                            const float* __restrict__ W,
                                            const float* __restrict__ bias,
                                            float* __restrict__ u2) {
  int b = blockIdx.x, t = threadIdx.x;
  __shared__ __align__(16) float su[NN];
  su[t] = u[b * NN + t];
  __syncthreads();
  const float4* su4 = (const float4*)su;
  const float4* W4  = (const float4*)(W + t * NN);
  float acc = bias[t];
  #pragma unroll 8
  for (int i = 0; i < NN / 4; ++i) {
    float4 wv = W4[i];
    float4 uv = su4[i];
    acc = fmaf(wv.x, uv.x, acc); acc = fmaf(wv.y, uv.y, acc);
    acc = fmaf(wv.z, uv.z, acc); acc = fmaf(wv.w, uv.w, acc);
  }
  u2[b * NN + t] = acc;
}

// ---------------- BatchNorm stats over batch ----------------
__global__ __launch_bounds__(256) void k_bn(const float* __restrict__ u2,
                                            const float* __restrict__ gamma,
                                            float* __restrict__ muv,
                                            float* __restrict__ invv) {
  int o = blockIdx.x, t = threadIdx.x;
  float v1 = u2[t * NN + o];
  float v2 = u2[(t + 256) * NN + o];
  __shared__ float rs[256], rq[256];
  rs[t] = v1 + v2;
  rq[t] = v1 * v1 + v2 * v2;
  __syncthreads();
  for (int off = 128; off > 0; off >>= 1) {
    if (t < off) { rs[t] += rs[t + off]; rq[t] += rq[t + off]; }
    __syncthreads();
  }
  if (t == 0) {
    float m   = rs[0] * (1.0f / NB);
    float var = rq[0] * (1.0f / NB) - m * m;
    muv[o]  = m;
    invv[o] = gamma[o] * rsqrtf(var + 1e-5f);
  }
}

// ---------------- GEMM1 (split-bf16 MFMA, 4 products): T[b] = Ws_b @ R_b ----------------
__global__ __launch_bounds__(256) void k_gemm1(const float* __restrict__ W,
                                               const float* __restrict__ s,
                                               const float* __restrict__ rho,
                                               float* __restrict__ T, int c0) {
  __shared__ ushort sAh[2048], sAl[2048], sBh[2048], sBl[2048];
  int t = threadIdx.x;
  int m0 = blockIdx.x * 128, n0 = blockIdx.y * 128;
  int bl = blockIdx.z, bg = c0 + bl;
  const float* Rb = rho + (size_t)bg * (NN * NN);
  const float* sb = s + bg * NN;
  int row = t >> 1, halfk = t & 1;
  int w = t >> 6, lane = t & 63;
  int mb0 = (w & 1) * 2, nb0 = (w >> 1) * 2;

  f32x16 acc[2][2] = {};

  const float* Aptr = W + (m0 + row) * NN + halfk * 8;
  const float* Bptr = Rb + (n0 + row) * NN + halfk * 8;
  const float* Sptr = sb + halfk * 8;
  float4 a0 = *(const float4*)(Aptr);
  float4 a1 = *(const float4*)(Aptr + 4);
  float4 b0 = *(const float4*)(Bptr);
  float4 b1 = *(const float4*)(Bptr + 4);
  float4 sv0 = *(const float4*)(Sptr);
  float4 sv1 = *(const float4*)(Sptr + 4);

  for (int kk = 0; kk < NN; kk += 16) {
    float4 as0 = make_float4(a0.x * sv0.x, a0.y * sv0.y, a0.z * sv0.z, a0.w * sv0.w);
    float4 as1 = make_float4(a1.x * sv1.x, a1.y * sv1.y, a1.z * sv1.z, a1.w * sv1.w);
    stage8(sAh, sAl, row, halfk, as0, as1);
    stage8(sBh, sBl, row, halfk, b0, b1);
    __syncthreads();
    if (kk + 16 < NN) {
      a0 = *(const float4*)(Aptr + kk + 16);
      a1 = *(const float4*)(Aptr + kk + 20);
      b0 = *(const float4*)(Bptr + kk + 16);
      b1 = *(const float4*)(Bptr + kk + 20);
      sv0 = *(const float4*)(Sptr + kk + 16);
      sv1 = *(const float4*)(Sptr + kk + 20);
    }
    bf16x8 ah[2], al[2], bh[2], blv[2];
    #pragma unroll
    for (int i = 0; i < 2; ++i) {
      ah[i]  = *(const bf16x8*)&sAh[((mb0 + i) * 64 + lane) * 8];
      al[i]  = *(const bf16x8*)&sAl[((mb0 + i) * 64 + lane) * 8];
      bh[i]  = *(const bf16x8*)&sBh[((nb0 + i) * 64 + lane) * 8];
      blv[i] = *(const bf16x8*)&sBl[((nb0 + i) * 64 + lane) * 8];
    }
    #pragma unroll
    for (int mi = 0; mi < 2; ++mi)
      #pragma unroll
      for (int ni = 0; ni < 2; ++ni) {
        acc[mi][ni] = __builtin_amdgcn_mfma_f32_32x32x16_bf16(ah[mi], bh[ni],  acc[mi][ni], 0, 0, 0);
        acc[mi][ni] = __builtin_amdgcn_mfma_f32_32x32x16_bf16(al[mi], bh[ni],  acc[mi][ni], 0, 0, 0);
        acc[mi][ni] = __builtin_amdgcn_mfma_f32_32x32x16_bf16(ah[mi], blv[ni], acc[mi][ni], 0, 0, 0);
        acc[mi][ni] = __builtin_amdgcn_mfma_f32_32x32x16_bf16(al[mi], blv[ni], acc[mi][ni], 0, 0, 0);
      }
    __syncthreads();
  }

  float* Tb = T + (size_t)bl * (NN * NN);
  int r2 = lane >> 5, col = lane & 31;
  int wm = (w & 1) * 64, wn = (w >> 1) * 64;
  #pragma unroll
  for (int mi = 0; mi < 2; ++mi)
    #pragma unroll
    for (int r = 0; r < 16; ++r) {
      int orow = m0 + wm + mi * 32 + (r & 3) + 8 * (r >> 2) + 4 * r2;
      #pragma unroll
      for (int ni = 0; ni < 2; ++ni) {
        int pcol = n0 + wn + ni * 32 + col;
        Tb[orow * NN + pcol] = acc[mi][ni][r];
      }
    }
}

// ---------------- diag: s2[b,o] = sqrt(max(sum_j T[b,o,j]*W[o,j]*s[b,j],0)) ----------------
__global__ __launch_bounds__(256) void k_diag(const float* __restrict__ T,
                                              const float* __restrict__ W,
                                              const float* __restrict__ s,
                                              float* __restrict__ s2v, int c0) {
  int wid = threadIdx.x >> 6, lane = threadIdx.x & 63;
  int idx = blockIdx.x * 4 + wid;
  int bl = idx >> 8, o = idx & 255;
  int bg = c0 + bl;
  const float* Trow = T + (size_t)bl * (NN * NN) + o * NN;
  const float* Wrow = W + o * NN;
  const float* sb = s + bg * NN;
  float4 tv = *(const float4*)(Trow + lane * 4);
  float4 wv = *(const float4*)(Wrow + lane * 4);
  float4 sv = *(const float4*)(sb + lane * 4);
  float p = tv.x * wv.x * sv.x + tv.y * wv.y * sv.y +
            tv.z * wv.z * sv.z + tv.w * wv.w * sv.w;
  for (int off = 32; off; off >>= 1) p += __shfl_down(p, off, 64);
  if (lane == 0) s2v[bg * NN + o] = sqrtf(fmaxf(p, 0.0f));
}

// ---------------- moment activation: u_a, s_a, chi (2 lanes per element) ----------------
__global__ __launch_bounds__(256) void k_act(const float* __restrict__ u2,
                                             const float* __restrict__ muv,
                                             const float* __restrict__ invv,
                                             const float* __restrict__ beta,
                                             const float* __restrict__ s2v,
                                             float* __restrict__ out_ua,
                                             float* __restrict__ out_sa,
                                             float* __restrict__ chiv, int c0) {
  int t = threadIdx.x;
  int e = blockIdx.x * 128 + (t >> 1);
  int half = t & 1;
  int bg = c0 + (e >> 8);
  int o = e & 255;
  int id = bg * NN + o;
  float iv  = invv[o];
  float ubn = fmaf(u2[id] - muv[o], iv, beta[o]);
  float sbn = s2v[id] * fabsf(iv);

  float ss = fmaxf(sbn, 1e-6f);
  float isl = 1.0f / (ss * SQRTL);
  float ub = fminf(fmaxf((1.0f - ubn) * isl, -4.0f), 4.0f);
  float lb = fminf(fmaxf((0.0f - ubn) * isl, -4.0f), 4.0f);
  float mid = 0.5f * (ub + lb), haf = 0.5f * (ub - lb);

  float I1 = 0.0f, V = 0.0f;
  for (int k = half; k < 16; k += 2) {
    float x  = fmaf(haf, GLN[k], mid);
    float E  = __expf(x * x);
    float EEx = fast_EE(x, E);
    I1 = fmaf(GLW[k], EEx, I1);
    float hm = 0.5f * (x + 4.0f);
    float tb = 0.5f * (x - 4.0f);
    float hs = 0.0f;
    #pragma unroll 4
    for (int j = 0; j < 16; ++j) {
      float tj = fmaf(hm, GLN[j], tb);
      float Et = __expf(tj * tj);
      float EEt = fast_EE(tj, Et);
      hs = fmaf(GLW[j], EEt * EEt * __builtin_amdgcn_rcpf(Et), hs);
    }
    V = fmaf(GLW[k], E * (hm * hs), V);
  }
  I1 += __shfl_xor(I1, 1);
  V  += __shfl_xor(V, 1);
  if (half == 0) {
    I1 *= haf; V *= haf;
    float u_a  = 1.0f / fmaf(40.0f, I1, 5.0f);
    float varT = 3200.0f * V;
    float s_a  = sqrtf(fmaxf(u_a * u_a * u_a * varT, 0.0f));
    float gub = fast_EE(ub, __expf(ub * ub));
    float glb = fast_EE(lb, __expf(lb * lb));
    float chi  = u_a * u_a * 40.0f * (gub - glb) / (SQRTL * fmaxf(s_a, 1e-6f));
    out_ua[id] = u_a;
    out_sa[id] = s_a;
    chiv[id]   = chi;
  }
}

// ---------------- GEMM2 (split-bf16 MFMA): rho_a[b] = scale(T[b] @ Ws_b^T) ----------------
__global__ __launch_bounds__(256) void k_gemm2(const float* __restrict__ T,
                                               const float* __restrict__ W,
                                               const float* __restrict__ s,
                                               const float* __restrict__ s2v,
                                               const float* __restrict__ chiv,
                                               float* __restrict__ out_rho, int c0) {
  __shared__ ushort sAh[2048], sAl[2048], sBh[2048], sBl[2048];
  int t = threadIdx.x;
  int m0 = blockIdx.x * 128, n0 = blockIdx.y * 128;
  int bl = blockIdx.z, bg = c0 + bl;
  const float* Tb = T + (size_t)bl * (NN * NN);
  const float* sb = s + bg * NN;
  int row = t >> 1, halfk = t & 1;
  int w = t >> 6, lane = t & 63;
  int mb0 = (w & 1) * 2, nb0 = (w >> 1) * 2;

  f32x16 acc[2][2] = {};

  const float* Aptr = Tb + (m0 + row) * NN + halfk * 8;
  const float* Bptr = W + (n0 + row) * NN + halfk * 8;
  const float* Sptr = sb + halfk * 8;
  float4 a0 = *(const float4*)(Aptr);
  float4 a1 = *(const float4*)(Aptr + 4);
  float4 b0 = *(const float4*)(Bptr);
  float4 b1 = *(const float4*)(Bptr + 4);
  float4 sv0 = *(const float4*)(Sptr);
  float4 sv1 = *(const float4*)(Sptr + 4);

  for (int kk = 0; kk < NN; kk += 16) {
    float4 bs0 = make_float4(b0.x * sv0.x, b0.y * sv0.y, b0.z * sv0.z, b0.w * sv0.w);
    float4 bs1 = make_float4(b1.x * sv1.x, b1.y * sv1.y, b1.z * sv1.z, b1.w * sv1.w);
    stage8(sAh, sAl, row, halfk, a0, a1);
    stage8(sBh, sBl, row, halfk, bs0, bs1);
    __syncthreads();
    if (kk + 16 < NN) {
      a0 = *(const float4*)(Aptr + kk + 16);
      a1 = *(const float4*)(Aptr + kk + 20);
      b0 = *(const float4*)(Bptr + kk + 16);
      b1 = *(const float4*)(Bptr + kk + 20);
      sv0 = *(const float4*)(Sptr + kk + 16);
      sv1 = *(const float4*)(Sptr + kk + 20);
    }
    bf16x8 ah[2], al[2], bh[2], blv[2];
    #pragma unroll
    for (int i = 0; i < 2; ++i) {
      ah[i]  = *(const bf16x8*)&sAh[((mb0 + i) * 64 + lane) * 8];
      al[i]  = *(const bf16x8*)&sAl[((mb0 + i) * 64 + lane) * 8];
      bh[i]  = *(const bf16x8*)&sBh[((nb0 + i) * 64 + lane) * 8];
      blv[i] = *(const bf16x8*)&sBl[((nb0 + i) * 64 + lane) * 8];
    }
    #pragma unroll
    for (int mi = 0; mi < 2; ++mi)
      #pragma unroll
      for (int ni = 0; ni < 2; ++ni) {
        acc[mi][ni] = __builtin_amdgcn_mfma_f32_32x32x16_bf16(ah[mi], bh[ni],  acc[mi][ni], 0, 0, 0);
        acc[mi][ni] = __builtin_amdgcn_mfma_f32_32x32x16_bf16(al[mi], bh[ni],  acc[mi][ni], 0, 0, 0);
        acc[mi][ni] = __builtin_amdgcn_mfma_f32_32x32x16_bf16(ah[mi], blv[ni], acc[mi][ni], 0, 0, 0);
      }
    __syncthreads();
  }

  // epilogue: rho_a = cov * chi_o*chi_p / (s2_o*s2_p + 1e-12), diag = 1
  float* Ob = out_rho + (size_t)bg * (NN * NN);
  int r2 = lane >> 5, col = lane & 31;
  int wm = (w & 1) * 64, wn = (w >> 1) * 64;
  float chp[2], szp[2];
  #pragma unroll
  for (int ni = 0; ni < 2; ++ni) {
    int p = n0 + wn + ni * 32 + col;
    chp[ni] = chiv[bg * NN + p];
    szp[ni] = s2v[bg * NN + p];
  }
  #pragma unroll
  for (int mi = 0; mi < 2; ++mi)
    #pragma unroll
    for (int r = 0; r < 16; ++r) {
      int orow = m0 + wm + mi * 32 + (r & 3) + 8 * (r >> 2) + 4 * r2;
      float co = chiv[bg * NN + orow];
      float so = s2v[bg * NN + orow];
      #pragma unroll
      for (int ni = 0; ni < 2; ++ni) {
        int pcol = n0 + wn + ni * 32 + col;
        float v = acc[mi][ni][r] * co * chp[ni] *
                  __builtin_amdgcn_rcpf(fmaf(so, szp[ni], 1e-12f));
        if (orow == pcol) v = 1.0f;
        Ob[orow * NN + pcol] = v;
      }
    }
}

extern "C" void kernel_launch(void* const* d_in, const int* in_sizes, int n_in,
                              void* d_out, int out_size, void* d_ws, size_t ws_size,
                              hipStream_t stream) {
  (void)in_sizes; (void)n_in; (void)out_size;
  const float* u     = (const float*)d_in[0];
  const float* s     = (const float*)d_in[1];
  const float* rho   = (const float*)d_in[2];
  const float* W     = (const float*)d_in[3];
  const float* bias  = (const float*)d_in[4];
  const float* gamma = (const float*)d_in[5];
  const float* beta  = (const float*)d_in[6];

  float* out_ua  = (float*)d_out;
  float* out_sa  = out_ua + NB * NN;
  float* out_rho = out_sa + NB * NN;

  float* u2   = (float*)d_ws;
  float* s2v  = u2 + NB * NN;
  float* chiv = s2v + NB * NN;
  float* muv  = chiv + NB * NN;
  float* invv = muv + NN;
  float* T    = invv + NN;
  size_t used = (size_t)((char*)T - (char*)d_ws);
  size_t rem  = ws_size > used ? ws_size - used : 0;
  int chunk = (int)(rem / ((size_t)NN * NN * 4));
  if (chunk > NB) chunk = NB;
  if (chunk < 1) chunk = 1;

  k_u2<<<NB, 256, 0, stream>>>(u, W, bias, u2);
  k_bn<<<NN, 256, 0, stream>>>(u2, gamma, muv, invv);

  for (int c0 = 0; c0 < NB; c0 += chunk) {
    int cb = (NB - c0) < chunk ? (NB - c0) : chunk;
    dim3 gg(2, 2, cb);
    k_gemm1<<<gg, 256, 0, stream>>>(W, s, rho, T, c0);
    k_diag<<<cb * 64, 256, 0, stream>>>(T, W, s, s2v, c0);
    k_act<<<cb * 2, 256, 0, stream>>>(u2, muv, invv, beta, s2v, out_ua, out_sa, chiv, c0);
    k_gemm2<<<gg, 256, 0, stream>>>(T, W, s, s2v, chiv, out_rho, c0);
  }
}

// Round 4
// 391.978 us; speedup vs baseline: 1.7741x; 1.1402x over previous
//
#include <hip/hip_runtime.h>
#include <math.h>

#define NB 512
#define NN 256

typedef __bf16 bf16x8 __attribute__((ext_vector_type(8)));
typedef float f32x16 __attribute__((ext_vector_type(16)));

constexpr float C_ERF   = 0.88622692545275801f;   // sqrt(pi)/2
constexpr float SQRT_PI = 1.77245385090551603f;
constexpr float SQRTL   = 0.22360679774997896f;   // sqrt(0.05)

__device__ __constant__ float GLN[16] = {
  -0.98940093499164993f, -0.94457502307323258f, -0.86563120238783174f,
  -0.75540440835500303f, -0.61787624440264375f, -0.45801677765722739f,
  -0.28160355077925891f, -0.09501250983763744f,  0.09501250983763744f,
   0.28160355077925891f,  0.45801677765722739f,  0.61787624440264375f,
   0.75540440835500303f,  0.86563120238783174f,  0.94457502307323258f,
   0.98940093499164993f };
__device__ __constant__ float GLW[16] = {
   0.02715245941175409f, 0.06225352393864789f, 0.09515851168249278f,
   0.12462897125553387f, 0.14959598881657673f, 0.16915651939500254f,
   0.18260341504492358f, 0.18945061045506850f, 0.18945061045506850f,
   0.18260341504492358f, 0.16915651939500254f, 0.14959598881657673f,
   0.12462897125553387f, 0.09515851168249278f, 0.06225352393864789f,
   0.02715245941175409f };

// P(z) = sqrt(pi)/2 * erfcx(z), z >= 0  (NR rational, rel err ~1e-6)
__device__ __forceinline__ float fast_P(float z) {
  float r = __builtin_amdgcn_rcpf(fmaf(0.5f, z, 1.0f));
  float p = fmaf(r, 0.17087277f, -0.82215223f);
  p = fmaf(r, p, 1.48851587f);
  p = fmaf(r, p, -1.13520398f);
  p = fmaf(r, p, 0.27886807f);
  p = fmaf(r, p, -0.18628806f);
  p = fmaf(r, p, 0.09678418f);
  p = fmaf(r, p, 0.37409196f);
  p = fmaf(r, p, 1.00002368f);
  p = fmaf(r, p, -1.26551223f);
  return C_ERF * r * __expf(p);
}
// EE(x) = exp(x^2) * sqrt(pi)/2 * erfc(-x), given E = exp(x^2)
__device__ __forceinline__ float fast_EE(float x, float E) {
  float P = fast_P(fabsf(x));
  return x <= 0.0f ? P : fmaf(SQRT_PI, E, -P);
}

// ---------- bf16 split helpers (round-to-nearest hi and lo residual) ----------
__device__ __forceinline__ uint bfrn(float x) {
  uint u = __float_as_uint(x);
  return (u + 0x7fffu + ((u >> 16) & 1u)) >> 16;
}
__device__ __forceinline__ uint packhi(float a, float b) {
  return bfrn(a) | (bfrn(b) << 16);
}
__device__ __forceinline__ uint packlo(float a, float b, uint h) {
  float af = __uint_as_float(h << 16);
  float bf = __uint_as_float(h & 0xffff0000u);
  return bfrn(a - af) | (bfrn(b - bf) << 16);
}
// stage 8 consecutive-k floats of one row (0..255) into fragment-ordered planes
__device__ __forceinline__ void stage8(ushort* hiP, ushort* loP, int row, int halfk,
                                       float4 f0, float4 f1) {
  uint h0 = packhi(f0.x, f0.y), h1 = packhi(f0.z, f0.w);
  uint h2 = packhi(f1.x, f1.y), h3 = packhi(f1.z, f1.w);
  uint l0 = packlo(f0.x, f0.y, h0), l1 = packlo(f0.z, f0.w, h1);
  uint l2 = packlo(f1.x, f1.y, h2), l3 = packlo(f1.z, f1.w, h3);
  int base = ((row >> 5) * 64 + halfk * 32 + (row & 31)) * 8;
  *(uint4*)&hiP[base] = make_uint4(h0, h1, h2, h3);
  *(uint4*)&loP[base] = make_uint4(l0, l1, l2, l3);
}

// ---------------- u2 = u @ W^T + b ----------------
__global__ __launch_bounds__(256) void k_u2(const float* __restrict__ u,
                                            const float* __restrict__ W,
                                            const float* __restrict__ bias,
                                            float* __restrict__ u2) {
  int b = blockIdx.x, t = threadIdx.x;
  __shared__ __align__(16) float su[NN];
  su[t] = u[b * NN + t];
  __syncthreads();
  const float4* su4 = (const float4*)su;
  const float4* W4  = (const float4*)(W + t * NN);
  float acc = bias[t];
  #pragma unroll 8
  for (int i = 0; i < NN / 4; ++i) {
    float4 wv = W4[i];
    float4 uv = su4[i];
    acc = fmaf(wv.x, uv.x, acc); acc = fmaf(wv.y, uv.y, acc);
    acc = fmaf(wv.z, uv.z, acc); acc = fmaf(wv.w, uv.w, acc);
  }
  u2[b * NN + t] = acc;
}

// ---------------- BatchNorm stats over batch ----------------
__global__ __launch_bounds__(256) void k_bn(const float* __restrict__ u2,
                                            const float* __restrict__ gamma,
                                            float* __restrict__ muv,
                                            float* __restrict__ invv) {
  int o = blockIdx.x, t = threadIdx.x;
  float v1 = u2[t * NN + o];
  float v2 = u2[(t + 256) * NN + o];
  __shared__ float rs[256], rq[256];
  rs[t] = v1 + v2;
  rq[t] = v1 * v1 + v2 * v2;
  __syncthreads();
  for (int off = 128; off > 0; off >>= 1) {
    if (t < off) { rs[t] += rs[t + off]; rq[t] += rq[t + off]; }
    __syncthreads();
  }
  if (t == 0) {
    float m   = rs[0] * (1.0f / NB);
    float var = rq[0] * (1.0f / NB) - m * m;
    muv[o]  = m;
    invv[o] = gamma[o] * rsqrtf(var + 1e-5f);
  }
}

// ============ fused per-batch kernel: T=Ws*R (LDS) -> diag -> act -> rho_a ============
__global__ __launch_bounds__(512, 2) void k_fused(
    const float* __restrict__ W, const float* __restrict__ s,
    const float* __restrict__ rho, const float* __restrict__ u2,
    const float* __restrict__ muv, const float* __restrict__ invv,
    const float* __restrict__ beta, float* __restrict__ out_ua,
    float* __restrict__ out_sa, float* __restrict__ out_rho) {
  // LDS: T-hi bf16 128KB | A-hi 8K | A-lo 8K | B-hi 8K | B-lo 8K  (=160 KB)
  // after stage 1: s2/chi overlap the (then unused) A-hi region.
  __shared__ __align__(16) char lds[163840];
  ushort* Th = (ushort*)lds;
  ushort* Ah = (ushort*)(lds + 131072);
  ushort* Al = (ushort*)(lds + 139264);
  ushort* Bh = (ushort*)(lds + 147456);
  ushort* Bl = (ushort*)(lds + 155648);
  float* s2L  = (float*)(lds + 131072);
  float* chiL = (float*)(lds + 132096);

  int t = threadIdx.x;
  int bg = blockIdx.x;
  const float* Rb = rho + (size_t)bg * (NN * NN);
  const float* sb = s + bg * NN;
  int row = t >> 1, halfk = t & 1;
  int w = t >> 6, lane = t & 63;
  int wmt = (w & 3) * 2, wnt = (w >> 2) * 4;   // wave tile grid: 4 (m) x 2 (n-half)
  int wm = wmt * 32, wn = wnt * 32;

  f32x16 acc[2][4] = {};

  // ---------------- stage 1: T = (W*diag(s)) @ R, 3-product split-bf16 ----------------
  const float* Aptr = W  + row * NN + halfk * 8;
  const float* Bptr = Rb + row * NN + halfk * 8;
  const float* Sptr = sb + halfk * 8;
  float4 a0 = *(const float4*)(Aptr);
  float4 a1 = *(const float4*)(Aptr + 4);
  float4 b0 = *(const float4*)(Bptr);
  float4 b1 = *(const float4*)(Bptr + 4);
  float4 sv0 = *(const float4*)(Sptr);
  float4 sv1 = *(const float4*)(Sptr + 4);

  for (int kk = 0; kk < NN; kk += 16) {
    float4 as0 = make_float4(a0.x * sv0.x, a0.y * sv0.y, a0.z * sv0.z, a0.w * sv0.w);
    float4 as1 = make_float4(a1.x * sv1.x, a1.y * sv1.y, a1.z * sv1.z, a1.w * sv1.w);
    stage8(Ah, Al, row, halfk, as0, as1);
    stage8(Bh, Bl, row, halfk, b0, b1);
    __syncthreads();
    if (kk + 16 < NN) {
      a0 = *(const float4*)(Aptr + kk + 16);
      a1 = *(const float4*)(Aptr + kk + 20);
      b0 = *(const float4*)(Bptr + kk + 16);
      b1 = *(const float4*)(Bptr + kk + 20);
      sv0 = *(const float4*)(Sptr + kk + 16);
      sv1 = *(const float4*)(Sptr + kk + 20);
    }
    bf16x8 ahf[2], alf[2], bhf[4], blf[4];
    #pragma unroll
    for (int i = 0; i < 2; ++i) {
      ahf[i] = *(const bf16x8*)&Ah[((wmt + i) * 64 + lane) * 8];
      alf[i] = *(const bf16x8*)&Al[((wmt + i) * 64 + lane) * 8];
    }
    #pragma unroll
    for (int i = 0; i < 4; ++i) {
      bhf[i] = *(const bf16x8*)&Bh[((wnt + i) * 64 + lane) * 8];
      blf[i] = *(const bf16x8*)&Bl[((wnt + i) * 64 + lane) * 8];
    }
    #pragma unroll
    for (int mi = 0; mi < 2; ++mi)
      #pragma unroll
      for (int ni = 0; ni < 4; ++ni) {
        acc[mi][ni] = __builtin_amdgcn_mfma_f32_32x32x16_bf16(ahf[mi], bhf[ni], acc[mi][ni], 0, 0, 0);
        acc[mi][ni] = __builtin_amdgcn_mfma_f32_32x32x16_bf16(alf[mi], bhf[ni], acc[mi][ni], 0, 0, 0);
        acc[mi][ni] = __builtin_amdgcn_mfma_f32_32x32x16_bf16(ahf[mi], blf[ni], acc[mi][ni], 0, 0, 0);
      }
    __syncthreads();
  }

  // ---------------- T-hi -> LDS (xor-swizzled), zero s2 accumulators ----------------
  if (t < NN) s2L[t] = 0.0f;
  #pragma unroll
  for (int mi = 0; mi < 2; ++mi)
    #pragma unroll
    for (int ni = 0; ni < 4; ++ni)
      #pragma unroll
      for (int r = 0; r < 16; ++r) {
        int o = wm + mi * 32 + (r & 3) + 8 * (r >> 2) + 4 * (lane >> 5);
        int j = wn + ni * 32 + (lane & 31);
        Th[o * NN + ((((j >> 3) ^ (o & 31)) << 3) | (j & 7))] = (ushort)bfrn(acc[mi][ni][r]);
      }
  __syncthreads();

  // ---------------- diag from fp32 accumulators: s2[o] += sum_j T[o,j]*W[o,j]*s[j] ----------------
  {
    float sjv[4];
    #pragma unroll
    for (int ni = 0; ni < 4; ++ni) sjv[ni] = sb[wn + ni * 32 + (lane & 31)];
    #pragma unroll
    for (int mi = 0; mi < 2; ++mi)
      #pragma unroll
      for (int r = 0; r < 16; ++r) {
        int o = wm + mi * 32 + (r & 3) + 8 * (r >> 2) + 4 * (lane >> 5);
        float v = 0.0f;
        #pragma unroll
        for (int ni = 0; ni < 4; ++ni) {
          int j = wn + ni * 32 + (lane & 31);
          v = fmaf(acc[mi][ni][r], W[o * NN + j] * sjv[ni], v);
        }
        #pragma unroll
        for (int off = 16; off; off >>= 1) v += __shfl_xor(v, off);
        if ((lane & 31) == 0) atomicAdd(&s2L[o], v);
      }
  }
  __syncthreads();

  // ---------------- activation: u_a, s_a, chi (2 threads per element) ----------------
  {
    int e = t >> 1, half = t & 1;
    int id = bg * NN + e;
    float iv  = invv[e];
    float ubn = fmaf(u2[id] - muv[e], iv, beta[e]);
    float s2v = sqrtf(fmaxf(s2L[e], 0.0f));
    float sbn = s2v * fabsf(iv);
    float ss  = fmaxf(sbn, 1e-6f);
    float isl = 1.0f / (ss * SQRTL);
    float ub = fminf(fmaxf((1.0f - ubn) * isl, -4.0f), 4.0f);
    float lb = fminf(fmaxf((0.0f - ubn) * isl, -4.0f), 4.0f);
    float mid = 0.5f * (ub + lb), haf = 0.5f * (ub - lb);
    float I1 = 0.0f, V = 0.0f;
    for (int k = half; k < 16; k += 2) {
      float x  = fmaf(haf, GLN[k], mid);
      float E  = __expf(x * x);
      I1 = fmaf(GLW[k], fast_EE(x, E), I1);
      float hm = 0.5f * (x + 4.0f);
      float tb = 0.5f * (x - 4.0f);
      float hs = 0.0f;
      #pragma unroll 4
      for (int j = 0; j < 16; ++j) {
        float tj = fmaf(hm, GLN[j], tb);
        float Et = __expf(tj * tj);
        float EEt = fast_EE(tj, Et);
        hs = fmaf(GLW[j], EEt * EEt * __builtin_amdgcn_rcpf(Et), hs);
      }
      V = fmaf(GLW[k], E * (hm * hs), V);
    }
    I1 += __shfl_xor(I1, 1);
    V  += __shfl_xor(V, 1);
    if (half == 0) {
      I1 *= haf; V *= haf;
      float u_a  = 1.0f / fmaf(40.0f, I1, 5.0f);
      float varT = 3200.0f * V;
      float s_a  = sqrtf(fmaxf(u_a * u_a * u_a * varT, 0.0f));
      float gub = fast_EE(ub, __expf(ub * ub));
      float glb = fast_EE(lb, __expf(lb * lb));
      float chi = u_a * u_a * 40.0f * (gub - glb) / (SQRTL * fmaxf(s_a, 1e-6f));
      out_ua[id] = u_a;
      out_sa[id] = s_a;
      chiL[e] = chi;
      s2L[e]  = s2v;
    }
  }
  __syncthreads();

  // ---------------- stage 2: cov = T @ (W*diag(s))^T, T from LDS (bf16) ----------------
  #pragma unroll
  for (int mi = 0; mi < 2; ++mi)
    #pragma unroll
    for (int ni = 0; ni < 4; ++ni)
      #pragma unroll
      for (int r = 0; r < 16; ++r) acc[mi][ni][r] = 0.0f;

  b0 = *(const float4*)(Aptr);          // W row again (B-operand now)
  b1 = *(const float4*)(Aptr + 4);
  sv0 = *(const float4*)(Sptr);
  sv1 = *(const float4*)(Sptr + 4);

  for (int kk = 0; kk < NN; kk += 16) {
    float4 bs0 = make_float4(b0.x * sv0.x, b0.y * sv0.y, b0.z * sv0.z, b0.w * sv0.w);
    float4 bs1 = make_float4(b1.x * sv1.x, b1.y * sv1.y, b1.z * sv1.z, b1.w * sv1.w);
    stage8(Bh, Bl, row, halfk, bs0, bs1);
    __syncthreads();
    if (kk + 16 < NN) {
      b0 = *(const float4*)(Aptr + kk + 16);
      b1 = *(const float4*)(Aptr + kk + 20);
      sv0 = *(const float4*)(Sptr + kk + 16);
      sv1 = *(const float4*)(Sptr + kk + 20);
    }
    bf16x8 af[2], bhf[4], blf[4];
    #pragma unroll
    for (int i = 0; i < 2; ++i) {
      int ra = wm + i * 32 + (lane & 31);
      int jb = (kk >> 3) + (lane >> 5);
      af[i] = *(const bf16x8*)&Th[ra * NN + ((jb ^ (ra & 31)) << 3)];
    }
    #pragma unroll
    for (int i = 0; i < 4; ++i) {
      bhf[i] = *(const bf16x8*)&Bh[((wnt + i) * 64 + lane) * 8];
      blf[i] = *(const bf16x8*)&Bl[((wnt + i) * 64 + lane) * 8];
    }
    #pragma unroll
    for (int mi = 0; mi < 2; ++mi)
      #pragma unroll
      for (int ni = 0; ni < 4; ++ni) {
        acc[mi][ni] = __builtin_amdgcn_mfma_f32_32x32x16_bf16(af[mi], bhf[ni], acc[mi][ni], 0, 0, 0);
        acc[mi][ni] = __builtin_amdgcn_mfma_f32_32x32x16_bf16(af[mi], blf[ni], acc[mi][ni], 0, 0, 0);
      }
    __syncthreads();
  }

  // ---------------- epilogue: rho_a = cov * chi_o*chi_p / (s2_o*s2_p + 1e-12), diag=1 ----------------
  float chp[4], szp[4];
  #pragma unroll
  for (int ni = 0; ni < 4; ++ni) {
    int p = wn + ni * 32 + (lane & 31);
    chp[ni] = chiL[p];
    szp[ni] = s2L[p];
  }
  float* Ob = out_rho + (size_t)bg * (NN * NN);
  #pragma unroll
  for (int mi = 0; mi < 2; ++mi)
    #pragma unroll
    for (int r = 0; r < 16; ++r) {
      int o = wm + mi * 32 + (r & 3) + 8 * (r >> 2) + 4 * (lane >> 5);
      float co = chiL[o], so = s2L[o];
      #pragma unroll
      for (int ni = 0; ni < 4; ++ni) {
        int p = wn + ni * 32 + (lane & 31);
        float v = acc[mi][ni][r] * co * chp[ni] *
                  __builtin_amdgcn_rcpf(fmaf(so, szp[ni], 1e-12f));
        if (o == p) v = 1.0f;
        Ob[o * NN + p] = v;
      }
    }
}

extern "C" void kernel_launch(void* const* d_in, const int* in_sizes, int n_in,
                              void* d_out, int out_size, void* d_ws, size_t ws_size,
                              hipStream_t stream) {
  (void)in_sizes; (void)n_in; (void)out_size; (void)ws_size;
  const float* u     = (const float*)d_in[0];
  const float* s     = (const float*)d_in[1];
  const float* rho   = (const float*)d_in[2];
  const float* W     = (const float*)d_in[3];
  const float* bias  = (const float*)d_in[4];
  const float* gamma = (const float*)d_in[5];
  const float* beta  = (const float*)d_in[6];

  float* out_ua  = (float*)d_out;
  float* out_sa  = out_ua + NB * NN;
  float* out_rho = out_sa + NB * NN;

  float* u2   = (float*)d_ws;          // NB*NN
  float* muv  = u2 + NB * NN;          // NN
  float* invv = muv + NN;              // NN

  k_u2<<<NB, 256, 0, stream>>>(u, W, bias, u2);
  k_bn<<<NN, 256, 0, stream>>>(u2, gamma, muv, invv);
  k_fused<<<NB, 512, 0, stream>>>(W, s, rho, u2, muv, invv, beta,
                                  out_ua, out_sa, out_rho);
}